// Round 3
// baseline (661.566 us; speedup 1.0000x reference)
//
#include <hip/hip_runtime.h>

#define H 256
typedef unsigned int  uint;
typedef unsigned short ushort;
typedef float  floatx4 __attribute__((ext_vector_type(4)));
typedef short  shortx8 __attribute__((ext_vector_type(8)));

// ---- helpers ---------------------------------------------------------------
__device__ __forceinline__ ushort bf16rn(float f) {      // RNE f32->bf16
    uint u = __float_as_uint(f);
    u += 0x7FFF + ((u >> 16) & 1);
    return (ushort)(u >> 16);
}
__device__ __forceinline__ uint pkbf2(float a, float b) {
    return (uint)bf16rn(a) | ((uint)bf16rn(b) << 16);
}
__device__ __forceinline__ void atomic_pk_bf16(void* addr, uint v) {
    asm volatile("global_atomic_pk_add_bf16 %0, %1, off" :: "v"(addr), "v"(v) : "memory");
}

// ---------------------------------------------------------------------------
// prep: per out row r (1KB): bytes [0,512) = agg accumulator, zeroed;
//       bytes [512,1024) = bf16(ns row r). Replaces the memset AND gives the
//       GEMM a bf16 A operand it can load directly as MFMA fragments.
// ---------------------------------------------------------------------------
__global__ __launch_bounds__(256) void prep_kernel(
    const float* __restrict__ ns, char* __restrict__ outb, int M)
{
    long j = (long)blockIdx.x * 256 + threadIdx.x;   // one per column PAIR
    long row = j >> 7;
    int  p   = (int)(j & 127);
    if (row >= M) return;
    float2 v = ((const float2*)ns)[row * 128 + p];
    *(uint*)(outb + row * 1024 + p * 4)       = 0u;             // agg = 0
    *(uint*)(outb + row * 1024 + 512 + p * 4) = pkbf2(v.x, v.y); // nsb
}

// ---------------------------------------------------------------------------
// W (512x256 f32, k-major) -> Wt (256x512 bf16, n-major) into d_ws (256KB)
// ---------------------------------------------------------------------------
__global__ __launch_bounds__(256) void wt_kernel(const float* __restrict__ W,
                                                 ushort* __restrict__ Wt) {
    int k = blockIdx.x;          // 0..511
    int n = threadIdx.x;         // 0..255
    Wt[(size_t)n * 512 + k] = bf16rn(W[(size_t)k * H + n]);
}

// ---------------------------------------------------------------------------
// Scatter: 2 triples per 256-thread block; thread handles a column PAIR.
// Packed bf16x2 atomics into the agg half (first 512B) of each out row.
// At the measured L2 atomic ceiling (~292e9 atomics/s).
// ---------------------------------------------------------------------------
__global__ __launch_bounds__(256) void scatter_kernel(
    const float* __restrict__ ns, const float* __restrict__ rs,
    const int* __restrict__ trip, char* __restrict__ outbase, int n_trip)
{
    int t = blockIdx.x * 2 + (threadIdx.x >> 7);
    if (t >= n_trip) return;
    int p = threadIdx.x & 127;
    int s = trip[3 * t + 0];
    int r = trip[3 * t + 1];
    int o = trip[3 * t + 2];
    float2 vs = ((const float2*)ns)[(size_t)s * 128 + p];
    float2 vo = ((const float2*)ns)[(size_t)o * 128 + p];
    float2 vr = ((const float2*)rs)[(size_t)r * 128 + p];
    uint m_s2o = pkbf2(vs.x + vr.x, vs.y + vr.y);    // -> agg[o]
    uint m_o2s = pkbf2(vo.x + vr.x, vo.y + vr.y);    // -> agg[s]
    atomic_pk_bf16(outbase + (size_t)o * 1024 + p * 4, m_s2o);
    atomic_pk_bf16(outbase + (size_t)s * 1024 + p * 4, m_o2s);
}

// ---------------------------------------------------------------------------
// GEMM, barrier-free K-loop: out = ns + silu([ns|agg] @ W + b)
// Block = 64 rows x 256 cols; 4 waves, wave w -> cols [64w,64w+64) as 4x4
// 16x16x32 bf16 frags. A frags load DIRECT from the out-row buffer (nsb half
// for K<256, agg half for K>=256); B frags load DIRECT from Wt (L2-resident).
// No LDS, no K-loop barriers. One __syncthreads before the epilogue because
// out writes alias the agg/nsb bytes of the same rows (row-exclusive across
// blocks, but waves within a block read all 64 rows).
// ---------------------------------------------------------------------------
__global__ __launch_bounds__(256) void gemm_kernel(
    const float* __restrict__ ns, const char* __restrict__ rowbuf,
    const ushort* __restrict__ Wt, const float* __restrict__ bias,
    float* __restrict__ out, int M)
{
    const int tid  = threadIdx.x;
    const int wave = tid >> 6;
    const int lane = tid & 63;
    const int fm = lane & 15, fq = lane >> 4;
    const int rowBase = blockIdx.x * 64;

    long aoff[4];
#pragma unroll
    for (int mi = 0; mi < 4; ++mi) {
        int r = rowBase + mi * 16 + fm;
        if (r >= M) r = M - 1;
        aoff[mi] = (long)r * 1024;
    }
    const char* wb = (const char*)Wt;           // row stride 1024B (512 bf16)
    const long  bn[4] = { (long)(wave * 64 +  0 + fm) * 1024,
                          (long)(wave * 64 + 16 + fm) * 1024,
                          (long)(wave * 64 + 32 + fm) * 1024,
                          (long)(wave * 64 + 48 + fm) * 1024 };

    floatx4 acc[4][4] = {};                     // [mi][ni]

    // ---- phase A: K 0..255 (A = nsb, second half of row) ------------------
#pragma unroll
    for (int kt = 0; kt < 8; ++kt) {
        const int ko = kt * 64 + fq * 16;       // byte offset for this k-quad
        shortx8 aF[4], bF[4];
#pragma unroll
        for (int mi = 0; mi < 4; ++mi)
            aF[mi] = *(const shortx8*)(rowbuf + aoff[mi] + 512 + ko);
#pragma unroll
        for (int ni = 0; ni < 4; ++ni)
            bF[ni] = *(const shortx8*)(wb + bn[ni] + ko);
#pragma unroll
        for (int mi = 0; mi < 4; ++mi)
#pragma unroll
            for (int ni = 0; ni < 4; ++ni)
                acc[mi][ni] = __builtin_amdgcn_mfma_f32_16x16x32_bf16(
                    aF[mi], bF[ni], acc[mi][ni], 0, 0, 0);
    }
    // ---- phase B: K 256..511 (A = agg bf16, first half of row) ------------
#pragma unroll
    for (int kt = 0; kt < 8; ++kt) {
        const int ko = kt * 64 + fq * 16;
        shortx8 aF[4], bF[4];
#pragma unroll
        for (int mi = 0; mi < 4; ++mi)
            aF[mi] = *(const shortx8*)(rowbuf + aoff[mi] + ko);
#pragma unroll
        for (int ni = 0; ni < 4; ++ni)
            bF[ni] = *(const shortx8*)(wb + bn[ni] + 512 + ko);
#pragma unroll
        for (int mi = 0; mi < 4; ++mi)
#pragma unroll
            for (int ni = 0; ni < 4; ++ni)
                acc[mi][ni] = __builtin_amdgcn_mfma_f32_16x16x32_bf16(
                    aF[mi], bF[ni], acc[mi][ni], 0, 0, 0);
    }

    // all agg/nsb reads of this block's rows complete before any out write
    __syncthreads();

    // ---- epilogue: bias + SiLU + residual(fp32 ns) ------------------------
    // C/D layout: col = lane&15, row = (lane>>4)*4 + reg  [m89/m91 verified]
#pragma unroll
    for (int mi = 0; mi < 4; ++mi) {
#pragma unroll
        for (int ni = 0; ni < 4; ++ni) {
            int col = wave * 64 + ni * 16 + fm;
            float bc = bias[col];
#pragma unroll
            for (int r = 0; r < 4; ++r) {
                int row = rowBase + mi * 16 + fq * 4 + r;
                if (row < M) {
                    float x = acc[mi][ni][r] + bc;
                    float sg = 1.f / (1.f + __expf(-x));
                    out[(size_t)row * H + col] = ns[(size_t)row * H + col] + x * sg;
                }
            }
        }
    }
}

extern "C" void kernel_launch(void* const* d_in, const int* in_sizes, int n_in,
                              void* d_out, int out_size, void* d_ws, size_t ws_size,
                              hipStream_t stream)
{
    const float* ns   = (const float*)d_in[0];
    const float* rs   = (const float*)d_in[1];
    const int*   tp   = (const int*)d_in[2];
    const float* Wm   = (const float*)d_in[3];
    const float* bias = (const float*)d_in[4];
    const int M      = in_sizes[0] / H;      // 100000
    const int n_trip = in_sizes[2] / 3;      // 300000
    float*  out = (float*)d_out;
    ushort* Wt  = (ushort*)d_ws;             // 256KB

    prep_kernel<<<dim3((M * 128 + 255) / 256), dim3(256), 0, stream>>>(
        ns, (char*)d_out, M);
    wt_kernel<<<dim3(512), dim3(256), 0, stream>>>(Wm, Wt);
    scatter_kernel<<<dim3((n_trip + 1) / 2), dim3(256), 0, stream>>>(
        ns, rs, tp, (char*)d_out, n_trip);
    gemm_kernel<<<dim3((M + 63) / 64), dim3(256), 0, stream>>>(
        ns, (const char*)d_out, Wt, bias, out, M);
}